// Round 2
// baseline (369.664 us; speedup 1.0000x reference)
//
#include <hip/hip_runtime.h>
#include <hip/hip_bf16.h>

typedef __bf16 bf16x8 __attribute__((ext_vector_type(8)));
typedef __bf16 bf16x4 __attribute__((ext_vector_type(4)));
typedef float  f32x4  __attribute__((ext_vector_type(4)));

#define LAYERS 16
#define DIM 64
#define NHID 256
#define BATCH 32768
#define MTILE 64
#define NBLOCKS (BATCH / MTILE)   // 512

// packed weight sizes in bf16 elements
#define W0P_PER 16384             // per (net,layer): 16 ntiles * 2 ktiles * 512
#define W1P_PER 65536             // 16 ntiles * 8 ktiles * 512
#define W2P_PER 16384             // 4 ntiles * 8 ktiles * 512
#define W0P_TOT (32 * W0P_PER)    // 524288
#define W1P_TOT (32 * W1P_PER)    // 2097152
#define W2P_TOT (32 * W2P_PER)    // 524288
#define PACK_TOT (W0P_TOT + W1P_TOT + W2P_TOT)  // 3145728 bf16 = 6.29 MB

// ---------------------------------------------------------------------------
// Pack kernel: masked weights -> bf16, laid out in MFMA fragment order
// (identical for A- and B-operand use): per (net, layer, gemm):
// [otile][ktile][lane(64)][j(8)], element = W[o][k+j]*M[o][k+j] with
// o = otile*16 + (lane&15), k = ktile*32 + (lane>>4)*8.
// ---------------------------------------------------------------------------
__global__ __launch_bounds__(256) void pack_weights(
    const float* __restrict__ lW0, const float* __restrict__ lW1, const float* __restrict__ lW2,
    const float* __restrict__ sW0, const float* __restrict__ sW1, const float* __restrict__ sW2,
    const float* __restrict__ M0,  const float* __restrict__ M1,  const float* __restrict__ M2,
    __bf16* __restrict__ ws)
{
    const long i = ((long)blockIdx.x * 256 + threadIdx.x) * 8;  // elem base
    const float* W; const float* M; long src;
    if (i < W0P_TOT) {
        int netl = (int)(i / W0P_PER), rem = (int)(i % W0P_PER);
        int net = netl >> 4, l = netl & 15;
        int nt = rem >> 10, kt = (rem >> 9) & 1, lane = (rem >> 3) & 63;
        int n = nt * 16 + (lane & 15), k = kt * 32 + (lane >> 4) * 8;
        W = net ? sW0 : lW0; M = M0;
        src = (long)(l * 256 + n) * 64 + k;
    } else if (i < W0P_TOT + W1P_TOT) {
        long r = i - W0P_TOT;
        int netl = (int)(r / W1P_PER), rem = (int)(r % W1P_PER);
        int net = netl >> 4, l = netl & 15;
        int nt = rem >> 12, kt = (rem >> 9) & 7, lane = (rem >> 3) & 63;
        int n = nt * 16 + (lane & 15), k = kt * 32 + (lane >> 4) * 8;
        W = net ? sW1 : lW1; M = M1;
        src = (long)(l * 256 + n) * 256 + k;
    } else {
        long r = i - W0P_TOT - W1P_TOT;
        int netl = (int)(r / W2P_PER), rem = (int)(r % W2P_PER);
        int net = netl >> 4, l = netl & 15;
        int nt = rem >> 12, kt = (rem >> 9) & 7, lane = (rem >> 3) & 63;
        int n = nt * 16 + (lane & 15), k = kt * 32 + (lane >> 4) * 8;
        W = net ? sW2 : lW2; M = M2;
        src = (long)(l * 64 + n) * 256 + k;
    }
    f32x4 wa = *(const f32x4*)(W + src);
    f32x4 wb = *(const f32x4*)(W + src + 4);
    f32x4 ma = *(const f32x4*)(M + src);
    f32x4 mb = *(const f32x4*)(M + src + 4);
    bf16x8 o;
    o[0] = (__bf16)(wa[0] * ma[0]); o[1] = (__bf16)(wa[1] * ma[1]);
    o[2] = (__bf16)(wa[2] * ma[2]); o[3] = (__bf16)(wa[3] * ma[3]);
    o[4] = (__bf16)(wb[0] * mb[0]); o[5] = (__bf16)(wb[1] * mb[1]);
    o[6] = (__bf16)(wb[2] * mb[2]); o[7] = (__bf16)(wb[3] * mb[3]);
    *(bf16x8*)(ws + i) = o;
}

// ---------------------------------------------------------------------------
// Flow kernel, round 2: operand roles swapped (weights = A, activations = B).
// D layout: col(l16) = batch row, row(quad*4+r) = hidden/out dim -> epilogue
// writes are packed bf16x4 (b64), conflict-free with strides 72/264.
// 8 waves per 64-row block (512 thr), grid 512 -> 2 blocks/CU, 16 waves/CU.
// Activations [batch][feature] in LDS; weights read from global (L2-resident).
// ---------------------------------------------------------------------------
__global__ __launch_bounds__(512, 4) void flow_kernel(
    const float* __restrict__ u,
    const __bf16* __restrict__ wp,
    const float* __restrict__ lb0, const float* __restrict__ lb1, const float* __restrict__ lb2,
    const float* __restrict__ sb0, const float* __restrict__ sb1, const float* __restrict__ sb2,
    float* __restrict__ out)
{
    __shared__ __bf16 ybf[MTILE][72];    // y staging, stride 144 B (36 words)
    __shared__ __bf16 buf1[MTILE][264];  // h0, stride 528 B (132 words)
    __shared__ __bf16 buf2[MTILE][264];  // h1

    const int tid  = threadIdx.x;
    const int wave = tid >> 6;        // 0..7
    const int lane = tid & 63;
    const int quad = lane >> 4;
    const int l16  = lane & 15;
    const int blk  = blockIdx.x;

    const int whid = wave * 2;        // G1/G2: wave owns hidden tiles whid, whid+1
    const int mt3  = wave >> 1;       // G3: wave's out-dim tile (0..3)
    const int ntb  = (wave & 1) * 2;  // G3/y: wave's batch-tile base (0 or 2)

    const __bf16* w0p = wp;
    const __bf16* w1p = wp + W0P_TOT;
    const __bf16* w2p = wp + W0P_TOT + W1P_TOT;

    // y regs: y[ntl][r] = row (blk*64 + (ntb+ntl)*16 + l16), dim (mt3*16 + quad*4 + r)
    float y[2][4];
    #pragma unroll
    for (int ntl = 0; ntl < 2; ++ntl) {
        const float* src = u + (long)(blk * MTILE + (ntb + ntl) * 16 + l16) * DIM
                             + mt3 * 16 + quad * 4;
        f32x4 t = *(const f32x4*)src;
        #pragma unroll
        for (int r = 0; r < 4; ++r) y[ntl][r] = t[r];
    }

    for (int l = 0; l < LAYERS; ++l) {
        // stage y -> bf16 B-operand buffer (packed b64 writes)
        #pragma unroll
        for (int ntl = 0; ntl < 2; ++ntl) {
            bf16x4 v;
            #pragma unroll
            for (int r = 0; r < 4; ++r) v[r] = (__bf16)y[ntl][r];
            *(bf16x4*)&ybf[(ntb + ntl) * 16 + l16][mt3 * 16 + quad * 4] = v;
        }
        __syncthreads();  // B1: ybf ready

        float locr[2][4], scr[2][4];

        #pragma unroll
        for (int net = 0; net < 2; ++net) {
            const __bf16* w0b = w0p + (long)(net * 16 + l) * W0P_PER;
            const __bf16* w1b = w1p + (long)(net * 16 + l) * W1P_PER;
            const __bf16* w2b = w2p + (long)(net * 16 + l) * W2P_PER;
            const float* b0 = (net ? sb0 : lb0) + l * 256;
            const float* b1 = (net ? sb1 : lb1) + l * 256;
            const float* b2 = (net ? sb2 : lb2) + l * 64;

            // ---- G1: W0 (A) x y^T (B) -> h0^T; wave owns 32 hidden x 64 batch
            {
                f32x4 acc[2][4];
                #pragma unroll
                for (int mt = 0; mt < 2; ++mt)
                    #pragma unroll
                    for (int nt = 0; nt < 4; ++nt)
                        acc[mt][nt] = (f32x4){0.f, 0.f, 0.f, 0.f};
                #pragma unroll
                for (int kt = 0; kt < 2; ++kt) {
                    bf16x8 aw[2], bv[4];
                    #pragma unroll
                    for (int mt = 0; mt < 2; ++mt)
                        aw[mt] = *(const bf16x8*)(w0b + (long)((whid + mt) * 2 + kt) * 512 + lane * 8);
                    #pragma unroll
                    for (int nt = 0; nt < 4; ++nt)
                        bv[nt] = *(const bf16x8*)&ybf[nt * 16 + l16][kt * 32 + quad * 8];
                    #pragma unroll
                    for (int mt = 0; mt < 2; ++mt)
                        #pragma unroll
                        for (int nt = 0; nt < 4; ++nt)
                            acc[mt][nt] = __builtin_amdgcn_mfma_f32_16x16x32_bf16(aw[mt], bv[nt], acc[mt][nt], 0, 0, 0);
                }
                #pragma unroll
                for (int mt = 0; mt < 2; ++mt) {
                    f32x4 bias = *(const f32x4*)(b0 + (whid + mt) * 16 + quad * 4);
                    #pragma unroll
                    for (int nt = 0; nt < 4; ++nt) {
                        bf16x4 v;
                        #pragma unroll
                        for (int r = 0; r < 4; ++r)
                            v[r] = (__bf16)fmaxf(acc[mt][nt][r] + bias[r], 0.f);
                        *(bf16x4*)&buf1[nt * 16 + l16][(whid + mt) * 16 + quad * 4] = v;
                    }
                }
            }
            __syncthreads();  // B2: h0 ready

            // ---- G2: W1 (A) x h0^T (B) -> h1^T
            {
                f32x4 acc[2][4];
                #pragma unroll
                for (int mt = 0; mt < 2; ++mt)
                    #pragma unroll
                    for (int nt = 0; nt < 4; ++nt)
                        acc[mt][nt] = (f32x4){0.f, 0.f, 0.f, 0.f};
                #pragma unroll
                for (int kt = 0; kt < 8; ++kt) {
                    bf16x8 aw[2], bv[4];
                    #pragma unroll
                    for (int mt = 0; mt < 2; ++mt)
                        aw[mt] = *(const bf16x8*)(w1b + (long)((whid + mt) * 8 + kt) * 512 + lane * 8);
                    #pragma unroll
                    for (int nt = 0; nt < 4; ++nt)
                        bv[nt] = *(const bf16x8*)&buf1[nt * 16 + l16][kt * 32 + quad * 8];
                    #pragma unroll
                    for (int mt = 0; mt < 2; ++mt)
                        #pragma unroll
                        for (int nt = 0; nt < 4; ++nt)
                            acc[mt][nt] = __builtin_amdgcn_mfma_f32_16x16x32_bf16(aw[mt], bv[nt], acc[mt][nt], 0, 0, 0);
                }
                #pragma unroll
                for (int mt = 0; mt < 2; ++mt) {
                    f32x4 bias = *(const f32x4*)(b1 + (whid + mt) * 16 + quad * 4);
                    #pragma unroll
                    for (int nt = 0; nt < 4; ++nt) {
                        bf16x4 v;
                        #pragma unroll
                        for (int r = 0; r < 4; ++r)
                            v[r] = (__bf16)fmaxf(acc[mt][nt][r] + bias[r], 0.f);
                        *(bf16x4*)&buf2[nt * 16 + l16][(whid + mt) * 16 + quad * 4] = v;
                    }
                }
            }
            __syncthreads();  // B3: h1 ready (also all buf1 reads done)

            // ---- G3: W2 (A) x h1^T (B) -> wave's (16 out-dims x 32 batch) in regs
            {
                f32x4 acc[2];
                acc[0] = (f32x4){0.f, 0.f, 0.f, 0.f};
                acc[1] = (f32x4){0.f, 0.f, 0.f, 0.f};
                #pragma unroll
                for (int kt = 0; kt < 8; ++kt) {
                    bf16x8 aw = *(const bf16x8*)(w2b + (long)(mt3 * 8 + kt) * 512 + lane * 8);
                    #pragma unroll
                    for (int ntl = 0; ntl < 2; ++ntl) {
                        bf16x8 bv = *(const bf16x8*)&buf2[(ntb + ntl) * 16 + l16][kt * 32 + quad * 8];
                        acc[ntl] = __builtin_amdgcn_mfma_f32_16x16x32_bf16(aw, bv, acc[ntl], 0, 0, 0);
                    }
                }
                f32x4 bias = *(const f32x4*)(b2 + mt3 * 16 + quad * 4);
                if (net == 0) {
                    #pragma unroll
                    for (int ntl = 0; ntl < 2; ++ntl)
                        #pragma unroll
                        for (int r = 0; r < 4; ++r)
                            locr[ntl][r] = acc[ntl][r] + bias[r];
                } else {
                    #pragma unroll
                    for (int ntl = 0; ntl < 2; ++ntl)
                        #pragma unroll
                        for (int r = 0; r < 4; ++r)
                            scr[ntl][r] = acc[ntl][r] + bias[r];
                }
            }
            // no barrier after G3: next G1 writes buf1 (all reads drained at B3);
            // next G2's buf2 writes are behind next B2, after all G3 reads finish
        }

        // coupling update, pure registers: y = exp(-sc) * (y - loc)
        #pragma unroll
        for (int ntl = 0; ntl < 2; ++ntl)
            #pragma unroll
            for (int r = 0; r < 4; ++r)
                y[ntl][r] = __expf(-scr[ntl][r]) * (y[ntl][r] - locr[ntl][r]);
        // next ybf write is safe: all ybf readers (both nets' G1) are behind
        // this layer's B2 barriers, which every wave passed before B3
    }

    #pragma unroll
    for (int ntl = 0; ntl < 2; ++ntl) {
        f32x4 t;
        #pragma unroll
        for (int r = 0; r < 4; ++r) t[r] = y[ntl][r];
        float* dst = out + (long)(blk * MTILE + (ntb + ntl) * 16 + l16) * DIM
                         + mt3 * 16 + quad * 4;
        *(f32x4*)dst = t;
    }
}

extern "C" void kernel_launch(void* const* d_in, const int* in_sizes, int n_in,
                              void* d_out, int out_size, void* d_ws, size_t ws_size,
                              hipStream_t stream) {
    const float* u   = (const float*)d_in[0];
    const float* lW0 = (const float*)d_in[1];
    const float* lb0 = (const float*)d_in[2];
    const float* lW1 = (const float*)d_in[3];
    const float* lb1 = (const float*)d_in[4];
    const float* lW2 = (const float*)d_in[5];
    const float* lb2 = (const float*)d_in[6];
    const float* sW0 = (const float*)d_in[7];
    const float* sb0 = (const float*)d_in[8];
    const float* sW1 = (const float*)d_in[9];
    const float* sb1 = (const float*)d_in[10];
    const float* sW2 = (const float*)d_in[11];
    const float* sb2 = (const float*)d_in[12];
    const float* M0  = (const float*)d_in[13];
    const float* M1  = (const float*)d_in[14];
    const float* M2  = (const float*)d_in[15];

    if (ws_size < (size_t)PACK_TOT * sizeof(__bf16)) return;
    __bf16* ws = (__bf16*)d_ws;

    pack_weights<<<PACK_TOT / 8 / 256, 256, 0, stream>>>(
        lW0, lW1, lW2, sW0, sW1, sW2, M0, M1, M2, ws);
    flow_kernel<<<NBLOCKS, 512, 0, stream>>>(
        u, ws, lb0, lb1, lb2, sb0, sb1, sb2, (float*)d_out);
}

// Round 3
// 349.868 us; speedup vs baseline: 1.0566x; 1.0566x over previous
//
#include <hip/hip_runtime.h>
#include <hip/hip_bf16.h>

typedef __bf16 bf16x8 __attribute__((ext_vector_type(8)));
typedef __bf16 bf16x4 __attribute__((ext_vector_type(4)));
typedef float  f32x4  __attribute__((ext_vector_type(4)));

#define LAYERS 16
#define DIM 64
#define NHID 256
#define BATCH 32768
#define MTILE 64
#define NBLOCKS (BATCH / MTILE)   // 512

// packed weight sizes in bf16 elements
#define W0P_PER 16384             // per (net,layer): 16 otiles * 2 ktiles * 512
#define W1P_PER 65536             // 16 otiles * 8 ktiles * 512
#define W2P_PER 16384             // 4 otiles * 8 ktiles * 512
#define W0P_TOT (32 * W0P_PER)    // 524288
#define W1P_TOT (32 * W1P_PER)    // 2097152
#define W2P_TOT (32 * W2P_PER)    // 524288
#define PACK_TOT (W0P_TOT + W1P_TOT + W2P_TOT)  // 3145728 bf16 = 6.29 MB

__device__ __forceinline__ bf16x8 ldw(const __bf16* p) { return *(const bf16x8*)p; }

// ---------------------------------------------------------------------------
// Pack kernel (unchanged): masked weights -> bf16 in MFMA fragment order:
// per (net, layer, gemm): [otile][ktile][lane(64)][j(8)], element =
// W[o][k+j]*M[o][k+j] with o = otile*16 + (lane&15), k = ktile*32 + (lane>>4)*8.
// ---------------------------------------------------------------------------
__global__ __launch_bounds__(256) void pack_weights(
    const float* __restrict__ lW0, const float* __restrict__ lW1, const float* __restrict__ lW2,
    const float* __restrict__ sW0, const float* __restrict__ sW1, const float* __restrict__ sW2,
    const float* __restrict__ M0,  const float* __restrict__ M1,  const float* __restrict__ M2,
    __bf16* __restrict__ ws)
{
    const long i = ((long)blockIdx.x * 256 + threadIdx.x) * 8;  // elem base
    const float* W; const float* M; long src;
    if (i < W0P_TOT) {
        int netl = (int)(i / W0P_PER), rem = (int)(i % W0P_PER);
        int net = netl >> 4, l = netl & 15;
        int nt = rem >> 10, kt = (rem >> 9) & 1, lane = (rem >> 3) & 63;
        int n = nt * 16 + (lane & 15), k = kt * 32 + (lane >> 4) * 8;
        W = net ? sW0 : lW0; M = M0;
        src = (long)(l * 256 + n) * 64 + k;
    } else if (i < W0P_TOT + W1P_TOT) {
        long r = i - W0P_TOT;
        int netl = (int)(r / W1P_PER), rem = (int)(r % W1P_PER);
        int net = netl >> 4, l = netl & 15;
        int nt = rem >> 12, kt = (rem >> 9) & 7, lane = (rem >> 3) & 63;
        int n = nt * 16 + (lane & 15), k = kt * 32 + (lane >> 4) * 8;
        W = net ? sW1 : lW1; M = M1;
        src = (long)(l * 256 + n) * 256 + k;
    } else {
        long r = i - W0P_TOT - W1P_TOT;
        int netl = (int)(r / W2P_PER), rem = (int)(r % W2P_PER);
        int net = netl >> 4, l = netl & 15;
        int nt = rem >> 12, kt = (rem >> 9) & 7, lane = (rem >> 3) & 63;
        int n = nt * 16 + (lane & 15), k = kt * 32 + (lane >> 4) * 8;
        W = net ? sW2 : lW2; M = M2;
        src = (long)(l * 64 + n) * 256 + k;
    }
    f32x4 wa = *(const f32x4*)(W + src);
    f32x4 wb = *(const f32x4*)(W + src + 4);
    f32x4 ma = *(const f32x4*)(M + src);
    f32x4 mb = *(const f32x4*)(M + src + 4);
    bf16x8 o;
    o[0] = (__bf16)(wa[0] * ma[0]); o[1] = (__bf16)(wa[1] * ma[1]);
    o[2] = (__bf16)(wa[2] * ma[2]); o[3] = (__bf16)(wa[3] * ma[3]);
    o[4] = (__bf16)(wb[0] * mb[0]); o[5] = (__bf16)(wb[1] * mb[1]);
    o[6] = (__bf16)(wb[2] * mb[2]); o[7] = (__bf16)(wb[3] * mb[3]);
    *(bf16x8*)(ws + i) = o;
}

// ---------------------------------------------------------------------------
// Flow kernel, round 3: identical dataflow to round 2 (weights = A,
// activations = B, 8 waves / 64-row block, 5 barriers/layer) + explicit
// CROSS-BARRIER WEIGHT PREFETCH: each phase's weight fragments are issued
// during the previous phase (before the barrier), so the post-barrier
// critical path no longer eats the L2 load latency cold.
//   wg1[4]  : G1 weights, issued in previous G2's epilogue
//   wg2a[8] : G2 weights kt=0..3, issued in G1's epilogue
//   wg3[8]  : G3 weights, issued in G2's epilogue
// ---------------------------------------------------------------------------
__global__ __launch_bounds__(512, 4) void flow_kernel(
    const float* __restrict__ u,
    const __bf16* __restrict__ wp,
    const float* __restrict__ lb0, const float* __restrict__ lb1, const float* __restrict__ lb2,
    const float* __restrict__ sb0, const float* __restrict__ sb1, const float* __restrict__ sb2,
    float* __restrict__ out)
{
    __shared__ __bf16 ybf[MTILE][72];    // y staging, stride 144 B
    __shared__ __bf16 buf1[MTILE][264];  // h0, stride 528 B
    __shared__ __bf16 buf2[MTILE][264];  // h1

    const int tid  = threadIdx.x;
    const int wave = tid >> 6;        // 0..7
    const int lane = tid & 63;
    const int quad = lane >> 4;
    const int l16  = lane & 15;
    const int blk  = blockIdx.x;

    const int whid = wave * 2;        // G1/G2: wave owns hidden tiles whid, whid+1
    const int mt3  = wave >> 1;       // G3: wave's out-dim tile (0..3)
    const int ntb  = (wave & 1) * 2;  // G3/y: wave's batch-tile base (0 or 2)

    const __bf16* w0p = wp;
    const __bf16* w1p = wp + W0P_TOT;
    const __bf16* w2p = wp + W0P_TOT + W1P_TOT;

    // y regs: y[ntl][r] = row (blk*64 + (ntb+ntl)*16 + l16), dim (mt3*16 + quad*4 + r)
    float y[2][4];
    #pragma unroll
    for (int ntl = 0; ntl < 2; ++ntl) {
        const float* src = u + (long)(blk * MTILE + (ntb + ntl) * 16 + l16) * DIM
                             + mt3 * 16 + quad * 4;
        f32x4 t = *(const f32x4*)src;
        #pragma unroll
        for (int r = 0; r < 4; ++r) y[ntl][r] = t[r];
    }

    // prime the pipeline: G1 weights for (net0, layer0)
    bf16x8 wg1[4];
    #pragma unroll
    for (int mt = 0; mt < 2; ++mt)
        #pragma unroll
        for (int kt = 0; kt < 2; ++kt)
            wg1[mt * 2 + kt] = ldw(w0p + (long)((whid + mt) * 2 + kt) * 512 + lane * 8);

    for (int l = 0; l < LAYERS; ++l) {
        // stage y -> bf16 B-operand buffer (packed b64 writes)
        #pragma unroll
        for (int ntl = 0; ntl < 2; ++ntl) {
            bf16x4 v;
            #pragma unroll
            for (int r = 0; r < 4; ++r) v[r] = (__bf16)y[ntl][r];
            *(bf16x4*)&ybf[(ntb + ntl) * 16 + l16][mt3 * 16 + quad * 4] = v;
        }
        __syncthreads();  // B1: ybf ready

        float locr[2][4], scr[2][4];

        #pragma unroll
        for (int net = 0; net < 2; ++net) {
            const __bf16* w1b = w1p + (long)(net * 16 + l) * W1P_PER;
            const __bf16* w2b = w2p + (long)(net * 16 + l) * W2P_PER;
            // next G1 slot: net0 -> (net1, l); net1 -> (net0, l+1). l=15/net1
            // lands on slot 16 (net1,l0): in-bounds, values unused.
            const __bf16* w0n = w0p + (long)(net == 0 ? 16 + l : l + 1) * W0P_PER;
            const float* b0 = (net ? sb0 : lb0) + l * 256;
            const float* b1 = (net ? sb1 : lb1) + l * 256;
            const float* b2 = (net ? sb2 : lb2) + l * 64;

            bf16x8 wg2a[8];

            // ---- G1: W0 (A, prefetched) x y^T (B) -> h0^T
            {
                f32x4 acc[2][4];
                #pragma unroll
                for (int mt = 0; mt < 2; ++mt)
                    #pragma unroll
                    for (int nt = 0; nt < 4; ++nt)
                        acc[mt][nt] = (f32x4){0.f, 0.f, 0.f, 0.f};
                #pragma unroll
                for (int kt = 0; kt < 2; ++kt) {
                    bf16x8 bv[4];
                    #pragma unroll
                    for (int nt = 0; nt < 4; ++nt)
                        bv[nt] = *(const bf16x8*)&ybf[nt * 16 + l16][kt * 32 + quad * 8];
                    #pragma unroll
                    for (int mt = 0; mt < 2; ++mt)
                        #pragma unroll
                        for (int nt = 0; nt < 4; ++nt)
                            acc[mt][nt] = __builtin_amdgcn_mfma_f32_16x16x32_bf16(wg1[mt * 2 + kt], bv[nt], acc[mt][nt], 0, 0, 0);
                }
                // prefetch G2 kt=0..3 across the upcoming barrier
                #pragma unroll
                for (int kt = 0; kt < 4; ++kt)
                    #pragma unroll
                    for (int mt = 0; mt < 2; ++mt)
                        wg2a[kt * 2 + mt] = ldw(w1b + (long)((whid + mt) * 8 + kt) * 512 + lane * 8);
                // epilogue
                #pragma unroll
                for (int mt = 0; mt < 2; ++mt) {
                    f32x4 bias = *(const f32x4*)(b0 + (whid + mt) * 16 + quad * 4);
                    #pragma unroll
                    for (int nt = 0; nt < 4; ++nt) {
                        bf16x4 v;
                        #pragma unroll
                        for (int r = 0; r < 4; ++r)
                            v[r] = (__bf16)fmaxf(acc[mt][nt][r] + bias[r], 0.f);
                        *(bf16x4*)&buf1[nt * 16 + l16][(whid + mt) * 16 + quad * 4] = v;
                    }
                }
            }
            __syncthreads();  // B2: h0 ready

            bf16x8 wg3[8];

            // ---- G2: W1 (A, kt<4 prefetched) x h0^T (B) -> h1^T
            {
                f32x4 acc[2][4];
                #pragma unroll
                for (int mt = 0; mt < 2; ++mt)
                    #pragma unroll
                    for (int nt = 0; nt < 4; ++nt)
                        acc[mt][nt] = (f32x4){0.f, 0.f, 0.f, 0.f};
                #pragma unroll
                for (int kt = 0; kt < 8; ++kt) {
                    bf16x8 aw[2];
                    #pragma unroll
                    for (int mt = 0; mt < 2; ++mt)
                        aw[mt] = (kt < 4) ? wg2a[kt * 2 + mt]
                                          : ldw(w1b + (long)((whid + mt) * 8 + kt) * 512 + lane * 8);
                    bf16x8 bv[4];
                    #pragma unroll
                    for (int nt = 0; nt < 4; ++nt)
                        bv[nt] = *(const bf16x8*)&buf1[nt * 16 + l16][kt * 32 + quad * 8];
                    #pragma unroll
                    for (int mt = 0; mt < 2; ++mt)
                        #pragma unroll
                        for (int nt = 0; nt < 4; ++nt)
                            acc[mt][nt] = __builtin_amdgcn_mfma_f32_16x16x32_bf16(aw[mt], bv[nt], acc[mt][nt], 0, 0, 0);
                }
                // prefetch G3 weights and next G1 weights across the barrier
                #pragma unroll
                for (int kt = 0; kt < 8; ++kt)
                    wg3[kt] = ldw(w2b + (long)(mt3 * 8 + kt) * 512 + lane * 8);
                #pragma unroll
                for (int mt = 0; mt < 2; ++mt)
                    #pragma unroll
                    for (int kt = 0; kt < 2; ++kt)
                        wg1[mt * 2 + kt] = ldw(w0n + (long)((whid + mt) * 2 + kt) * 512 + lane * 8);
                // epilogue
                #pragma unroll
                for (int mt = 0; mt < 2; ++mt) {
                    f32x4 bias = *(const f32x4*)(b1 + (whid + mt) * 16 + quad * 4);
                    #pragma unroll
                    for (int nt = 0; nt < 4; ++nt) {
                        bf16x4 v;
                        #pragma unroll
                        for (int r = 0; r < 4; ++r)
                            v[r] = (__bf16)fmaxf(acc[mt][nt][r] + bias[r], 0.f);
                        *(bf16x4*)&buf2[nt * 16 + l16][(whid + mt) * 16 + quad * 4] = v;
                    }
                }
            }
            __syncthreads();  // B3: h1 ready (also all buf1 reads done)

            // ---- G3: W2 (A, prefetched) x h1^T (B) -> regs
            {
                f32x4 acc[2];
                acc[0] = (f32x4){0.f, 0.f, 0.f, 0.f};
                acc[1] = (f32x4){0.f, 0.f, 0.f, 0.f};
                #pragma unroll
                for (int kt = 0; kt < 8; ++kt) {
                    #pragma unroll
                    for (int ntl = 0; ntl < 2; ++ntl) {
                        bf16x8 bv = *(const bf16x8*)&buf2[(ntb + ntl) * 16 + l16][kt * 32 + quad * 8];
                        acc[ntl] = __builtin_amdgcn_mfma_f32_16x16x32_bf16(wg3[kt], bv, acc[ntl], 0, 0, 0);
                    }
                }
                f32x4 bias = *(const f32x4*)(b2 + mt3 * 16 + quad * 4);
                if (net == 0) {
                    #pragma unroll
                    for (int ntl = 0; ntl < 2; ++ntl)
                        #pragma unroll
                        for (int r = 0; r < 4; ++r)
                            locr[ntl][r] = acc[ntl][r] + bias[r];
                } else {
                    #pragma unroll
                    for (int ntl = 0; ntl < 2; ++ntl)
                        #pragma unroll
                        for (int r = 0; r < 4; ++r)
                            scr[ntl][r] = acc[ntl][r] + bias[r];
                }
            }
            // no barrier after G3: next G1 writes buf1 (reads drained at B3);
            // next G2's buf2 writes are behind the next B2
        }

        // coupling update, pure registers: y = exp(-sc) * (y - loc)
        #pragma unroll
        for (int ntl = 0; ntl < 2; ++ntl)
            #pragma unroll
            for (int r = 0; r < 4; ++r)
                y[ntl][r] = __expf(-scr[ntl][r]) * (y[ntl][r] - locr[ntl][r]);
        // next ybf write safe: all ybf readers (both nets' G1) are behind this
        // layer's B2 barriers
    }

    #pragma unroll
    for (int ntl = 0; ntl < 2; ++ntl) {
        f32x4 t;
        #pragma unroll
        for (int r = 0; r < 4; ++r) t[r] = y[ntl][r];
        float* dst = out + (long)(blk * MTILE + (ntb + ntl) * 16 + l16) * DIM
                         + mt3 * 16 + quad * 4;
        *(f32x4*)dst = t;
    }
}

extern "C" void kernel_launch(void* const* d_in, const int* in_sizes, int n_in,
                              void* d_out, int out_size, void* d_ws, size_t ws_size,
                              hipStream_t stream) {
    const float* u   = (const float*)d_in[0];
    const float* lW0 = (const float*)d_in[1];
    const float* lb0 = (const float*)d_in[2];
    const float* lW1 = (const float*)d_in[3];
    const float* lb1 = (const float*)d_in[4];
    const float* lW2 = (const float*)d_in[5];
    const float* lb2 = (const float*)d_in[6];
    const float* sW0 = (const float*)d_in[7];
    const float* sb0 = (const float*)d_in[8];
    const float* sW1 = (const float*)d_in[9];
    const float* sb1 = (const float*)d_in[10];
    const float* sW2 = (const float*)d_in[11];
    const float* sb2 = (const float*)d_in[12];
    const float* M0  = (const float*)d_in[13];
    const float* M1  = (const float*)d_in[14];
    const float* M2  = (const float*)d_in[15];

    if (ws_size < (size_t)PACK_TOT * sizeof(__bf16)) return;
    __bf16* ws = (__bf16*)d_ws;

    pack_weights<<<PACK_TOT / 8 / 256, 256, 0, stream>>>(
        lW0, lW1, lW2, sW0, sW1, sW2, M0, M1, M2, ws);
    flow_kernel<<<NBLOCKS, 512, 0, stream>>>(
        u, ws, lb0, lb1, lb2, sb0, sb1, sb2, (float*)d_out);
}